// Round 8
// baseline (1476.110 us; speedup 1.0000x reference)
//
#include <hip/hip_runtime.h>

typedef __attribute__((ext_vector_type(8))) short short8_t;
typedef __attribute__((ext_vector_type(4))) float f32x4_t;

#define DDIM 128
#define BM   32
#define LDA  264   // ushort elems per LDS row: 528B stride, 16B aligned
#define NBLK 1024  // persistent blocks: 4/CU (LDS-limited), grid-stride over tiles

__device__ __forceinline__ unsigned short f2bf(float x) {
  union { float f; unsigned u; } v; v.f = x;
  unsigned r = v.u + 0x7FFFu + ((v.u >> 16) & 1u);   // RNE
  return (unsigned short)(r >> 16);
}

__device__ __forceinline__ float sigf(float x) {
  return __builtin_amdgcn_rcpf(1.0f + __expf(-x));
}
__device__ __forceinline__ float tanh_fast(float x) {
  return 2.0f * __builtin_amdgcn_rcpf(1.0f + __expf(-2.0f * x)) - 1.0f;
}

// Wt[c][k] = bf16(W[k][c]);  W:[256][640] f32, Wt:[640][256] bf16 (RNE)
__global__ void convert_w_kernel(const float* __restrict__ W,
                                 unsigned short* __restrict__ Wt,
                                 int twoD, int fiveD) {
  const int c = blockIdx.x;
  const int k = threadIdx.x;
  Wt[c * twoD + k] = f2bf(W[k * fiveD + c]);
}

__global__ __launch_bounds__(256, 4)
void treelstm_fused_kernel(const float* __restrict__ h_bot,
                           const float* __restrict__ c_bot,
                           const float* __restrict__ h_buf,
                           const float* __restrict__ c_buf,
                           const int* __restrict__ idx_bl,
                           const int* __restrict__ idx_pl,
                           const int* __restrict__ idx_br,
                           const int* __restrict__ idx_pr,
                           const float* __restrict__ bias,
                           const unsigned short* __restrict__ Wt,
                           float* __restrict__ out,
                           int K, int M, int ntiles) {
  __shared__ __align__(16) unsigned short A_lds[2][BM * LDA];   // 2 x 16.5 KB

  const int tid  = threadIdx.x;
  const int wave = tid >> 6;          // 0..3
  const int lane = tid & 63;
  const int l16  = lane & 15;
  const int lq   = lane >> 4;         // 0..3
  const int d0a  = wave * 16 + lq * 4;
  const int d0b  = d0a + 64;

  // staging role: 8 threads per row (2 halves x 4 col-segments), 1 idx/thread
  const int sr    = tid >> 3;         // 0..31 local row
  const int seg   = tid & 7;
  const int shalf = seg >> 2;         // 0: h_l, 1: h_r
  const int scs   = seg & 3;

  float* const out_h = out;
  float* const out_c = out + (size_t)M * DDIM;

  const int step = gridDim.x;
  int t = blockIdx.x;
  if (t >= ntiles) return;

#define SIDX(tt, dst)                                                        \
  { int m = (tt) * BM + sr; if (m >= M) m = M - 1;                           \
    if (shalf == 0) dst = (m < K) ? idx_bl[m] : idx_pl[m - K];               \
    else            dst = (m < K) ? idx_br[m] : idx_pr[m - K]; }

#define EPI_IDX(tt, dl, dr)                                                  \
  { _Pragma("unroll")                                                        \
    for (int mt = 0; mt < 2; ++mt) {                                         \
      int m = (tt) * BM + mt * 16 + l16; if (m >= M) m = M - 1;              \
      dl[mt] = (m < K) ? idx_bl[m] : idx_pl[m - K];                          \
      dr[mt] = (m < K) ? idx_br[m] : idx_pr[m - K]; } }

#define H_GATHER(tt, sidx, hv)                                               \
  { int m = (tt) * BM + sr; if (m >= M) m = M - 1;                           \
    const float* hb = (m < K) ? h_bot : h_buf;                               \
    const float4* s4 = (const float4*)(hb + (size_t)(sidx) * DDIM);          \
    _Pragma("unroll")                                                        \
    for (int q = 0; q < 8; ++q) hv[q] = s4[scs + 4 * q]; }

#define H_WRITE(bufp, hv)                                                    \
  { unsigned short* dst = &(bufp)[sr * LDA + shalf * DDIM];                  \
    _Pragma("unroll")                                                        \
    for (int q = 0; q < 8; ++q) {                                            \
      const int f4i = scs + 4 * q;                                           \
      ushort4 u;                                                             \
      u.x = f2bf(hv[q].x); u.y = f2bf(hv[q].y);                              \
      u.z = f2bf(hv[q].z); u.w = f2bf(hv[q].w);                              \
      *(ushort4*)(dst + f4i * 4) = u; } }

#define C_GATHER(tt, dl, dr, D0, cl, cr)                                     \
  { _Pragma("unroll")                                                        \
    for (int mt = 0; mt < 2; ++mt) {                                         \
      int m = (tt) * BM + mt * 16 + l16; if (m >= M) m = M - 1;              \
      const float* cb = (m < K) ? c_bot : c_buf;                             \
      cl[mt] = *(const f32x4_t*)(cb + (size_t)dl[mt] * DDIM + (D0));         \
      cr[mt] = *(const f32x4_t*)(cb + (size_t)dr[mt] * DDIM + (D0)); } }

#define GEMM_PASS(bufp, DBLK, D0, CL, CR)                                    \
  {                                                                          \
    f32x4_t acc[2][5];                                                       \
    _Pragma("unroll")                                                        \
    for (int mt = 0; mt < 2; ++mt)                                           \
      _Pragma("unroll")                                                      \
      for (int g = 0; g < 5; ++g) {                                          \
        f32x4_t z = {0.0f, 0.0f, 0.0f, 0.0f};                                \
        acc[mt][g] = z;                                                      \
      }                                                                      \
    const unsigned short* wb = Wt + (size_t)((DBLK) * 16 + l16) * 256 + lq * 8; \
    const int ab = l16 * LDA + lq * 8;                                       \
    _Pragma("unroll")                                                        \
    for (int kk = 0; kk < 8; ++kk) {                                         \
      const int k0 = kk * 32;                                                \
      short8_t hf[2];                                                        \
      _Pragma("unroll")                                                      \
      for (int mt = 0; mt < 2; ++mt)                                         \
        hf[mt] = *(const short8_t*)(&(bufp)[ab + mt * (16 * LDA) + k0]);     \
      _Pragma("unroll")                                                      \
      for (int g = 0; g < 5; ++g) {                                          \
        const short8_t wf =                                                  \
            *(const short8_t*)(wb + (size_t)g * (128 * 256) + k0);           \
        _Pragma("unroll")                                                    \
        for (int mt = 0; mt < 2; ++mt)                                       \
          acc[mt][g] = __builtin_amdgcn_mfma_f32_16x16x32_bf16(              \
              wf, hf[mt], acc[mt][g], 0, 0, 0);                              \
      }                                                                      \
    }                                                                        \
    f32x4_t bs[5];                                                           \
    _Pragma("unroll")                                                        \
    for (int g = 0; g < 5; ++g)                                              \
      bs[g] = *(const f32x4_t*)(bias + g * DDIM + (D0));                     \
    _Pragma("unroll")                                                        \
    for (int mt = 0; mt < 2; ++mt) {                                         \
      const int m = t * BM + mt * 16 + l16;                                  \
      if (m < M) {                                                           \
        f32x4_t hv4, cv4;                                                    \
        _Pragma("unroll")                                                    \
        for (int j = 0; j < 4; ++j) {                                        \
          const float gi = acc[mt][0][j] + bs[0][j];                         \
          const float go = acc[mt][1][j] + bs[1][j];                         \
          const float gu = acc[mt][2][j] + bs[2][j];                         \
          const float gl = acc[mt][3][j] + bs[3][j];                         \
          const float gr = acc[mt][4][j] + bs[4][j];                         \
          const float cn = sigf(gi) * tanh_fast(gu)                          \
                         + sigf(gl) * CL[mt][j] + sigf(gr) * CR[mt][j];      \
          const float hn = sigf(go) * tanh_fast(cn);                         \
          cv4[j] = cn; hv4[j] = hn;                                          \
        }                                                                    \
        const size_t off = (size_t)m * DDIM + (D0);                         \
        *(f32x4_t*)(out_h + off) = hv4;                                      \
        *(f32x4_t*)(out_c + off) = cv4;                                      \
      }                                                                      \
    }                                                                        \
  }

  // ---- prologue: stage tile t into buf0; prefetch idx state ----
  int il[2], ir[2];
  EPI_IDX(t, il, ir);
  {
    int s0; SIDX(t, s0);
    float4 hv0[8];
    H_GATHER(t, s0, hv0);
    H_WRITE(A_lds[0], hv0);
  }
  int sidx_n = 0;
  if (t + step < ntiles) SIDX(t + step, sidx_n);
  __syncthreads();

  int cur = 0;
  for (;;) {
    const int tn = t + step;
    const bool more = (tn < ntiles);
    unsigned short* const bufc = A_lds[cur];
    unsigned short* const bufn = A_lds[cur ^ 1];

    // (1) next tile's h gathers in flight (uses sidx prefetched last iter)
    float4 hv[8];
    if (more) H_GATHER(tn, sidx_n, hv);

    // (2) pass-0 c gathers in flight (consumed at end of pass 0)
    f32x4_t cl0[2], cr0[2];
    C_GATHER(t, il, ir, d0a, cl0, cr0);

    // (3) prefetch idx state for the next iteration
    int sidx_n2 = 0;
    int il_n[2], ir_n[2];
    if (tn + step < ntiles) SIDX(tn + step, sidx_n2);
    if (more) EPI_IDX(tn, il_n, ir_n);

    // (4) GEMM pass 0 + epilogue (hides (1)-(3) latency)
    GEMM_PASS(bufc, wave, d0a, cl0, cr0);

    // (5) stage next tile (h arrived under pass 0)
    if (more) H_WRITE(bufn, hv);

    // (6) pass-1 c gathers, then GEMM pass 1 + epilogue
    f32x4_t cl1[2], cr1[2];
    C_GATHER(t, il, ir, d0b, cl1, cr1);
    GEMM_PASS(bufc, wave + 4, d0b, cl1, cr1);

    if (!more) break;
    sidx_n = sidx_n2;
    il[0] = il_n[0]; il[1] = il_n[1];
    ir[0] = ir_n[0]; ir[1] = ir_n[1];
    t = tn;
    __syncthreads();   // buf[cur^1] staged; buf[cur] reads done -> safe to flip
    cur ^= 1;
  }
#undef SIDX
#undef EPI_IDX
#undef H_GATHER
#undef H_WRITE
#undef C_GATHER
#undef GEMM_PASS
}

extern "C" void kernel_launch(void* const* d_in, const int* in_sizes, int n_in,
                              void* d_out, int out_size, void* d_ws, size_t ws_size,
                              hipStream_t stream) {
  const float* h_bot  = (const float*)d_in[0];
  const float* c_bot  = (const float*)d_in[1];
  const float* h_buf  = (const float*)d_in[2];
  const float* c_buf  = (const float*)d_in[3];
  const int*   idx_bl = (const int*)d_in[4];
  const int*   idx_pl = (const int*)d_in[5];
  const int*   idx_br = (const int*)d_in[6];
  const int*   idx_pr = (const int*)d_in[7];
  const float* W      = (const float*)d_in[8];
  const float* bias   = (const float*)d_in[9];

  const int K = in_sizes[4];
  const int M = 2 * K;
  const int fiveD = in_sizes[9];               // 640
  const int twoD  = in_sizes[8] / fiveD;       // 256

  unsigned short* Wt = (unsigned short*)d_ws;  // [640][256] bf16 = 320 KB

  hipLaunchKernelGGL(convert_w_kernel, dim3(fiveD), dim3(twoD), 0, stream,
                     W, Wt, twoD, fiveD);

  const int ntiles = (M + BM - 1) / BM;
  const int grid = (ntiles < NBLK) ? ntiles : NBLK;
  hipLaunchKernelGGL(treelstm_fused_kernel, dim3(grid), dim3(256), 0, stream,
                     h_bot, c_bot, h_buf, c_buf,
                     idx_bl, idx_pl, idx_br, idx_pr,
                     bias, Wt, (float*)d_out, K, M, ntiles);
}

// Round 9
// 1151.152 us; speedup vs baseline: 1.2823x; 1.2823x over previous
//
#include <hip/hip_runtime.h>

typedef __attribute__((ext_vector_type(8))) short short8_t;
typedef __attribute__((ext_vector_type(4))) float f32x4_t;

#define DDIM 128

__device__ __forceinline__ unsigned short f2bf(float x) {
  union { float f; unsigned u; } v; v.f = x;
  unsigned r = v.u + 0x7FFFu + ((v.u >> 16) & 1u);   // RNE
  return (unsigned short)(r >> 16);
}

__device__ __forceinline__ float sigf(float x) {
  return __builtin_amdgcn_rcpf(1.0f + __expf(-x));
}
__device__ __forceinline__ float tanh_fast(float x) {
  return 2.0f * __builtin_amdgcn_rcpf(1.0f + __expf(-2.0f * x)) - 1.0f;
}

// pack two f32 bit-patterns into one u32 of two bf16 (truncate; h operand only)
__device__ __forceinline__ unsigned pk2(unsigned lo, unsigned hi) {
  return (hi & 0xFFFF0000u) | (lo >> 16);
}

// Wt[c][k] = bf16(W[k][c]);  W:[256][640] f32, Wt:[640][256] bf16 (RNE)
__global__ void convert_w_kernel(const float* __restrict__ W,
                                 unsigned short* __restrict__ Wt,
                                 int twoD, int fiveD) {
  const int c = blockIdx.x;
  const int k = threadIdx.x;
  Wt[c * twoD + k] = f2bf(W[k * fiveD + c]);
}

// Barrier-free, LDS-free: each wave gathers its MFMA B-fragments directly.
// Block = 4 waves, one 16-row m-tile; wave w owns output cols d in [32w, 32w+32).
__global__ __launch_bounds__(256, 4)
void treelstm_fused_kernel(const float* __restrict__ h_bot,
                           const float* __restrict__ c_bot,
                           const float* __restrict__ h_buf,
                           const float* __restrict__ c_buf,
                           const int* __restrict__ idx_bl,
                           const int* __restrict__ idx_pl,
                           const int* __restrict__ idx_br,
                           const int* __restrict__ idx_pr,
                           const float* __restrict__ bias,
                           const unsigned short* __restrict__ Wt,
                           float* __restrict__ out,
                           int K, int M) {
  const int tid  = threadIdx.x;
  const int w    = tid >> 6;          // 0..3
  const int lane = tid & 63;
  const int l16  = lane & 15;         // m-row within tile; B-frag col
  const int lq   = lane >> 4;         // 0..3; k-subchunk + output d-subrow
  const int d0a  = w * 32 + lq * 4;   // dblk 2w
  const int d0b  = d0a + 16;          // dblk 2w+1

  int m = blockIdx.x * 16 + l16;
  const bool valid = (m < M);
  if (!valid) m = M - 1;

  // ---- indices (left/right rows for this lane's m) ----
  const int il = (m < K) ? idx_bl[m] : idx_pl[m - K];
  const int ir = (m < K) ? idx_br[m] : idx_pr[m - K];
  const float* const hb = (m < K) ? h_bot : h_buf;
  const float* const cb = (m < K) ? c_bot : c_buf;

  // ---- issue all h gathers: per side 4 k-chunks x 32B (B-frag pattern) ----
  const float* const hl = hb + (size_t)il * DDIM + lq * 8;
  const float* const hr = hb + (size_t)ir * DDIM + lq * 8;
  f32x4_t hL[8], hR[8];
  #pragma unroll
  for (int k2 = 0; k2 < 4; ++k2) {
    hL[2 * k2]     = *(const f32x4_t*)(hl + k2 * 32);
    hL[2 * k2 + 1] = *(const f32x4_t*)(hl + k2 * 32 + 4);
    hR[2 * k2]     = *(const f32x4_t*)(hr + k2 * 32);
    hR[2 * k2 + 1] = *(const f32x4_t*)(hr + k2 * 32 + 4);
  }

  // ---- issue c gathers now; consumed after GEMM (latency hidden under it) ----
  const float* const clp = cb + (size_t)il * DDIM;
  const float* const crp = cb + (size_t)ir * DDIM;
  const f32x4_t cl0 = *(const f32x4_t*)(clp + d0a);
  const f32x4_t cl1 = *(const f32x4_t*)(clp + d0b);
  const f32x4_t cr0 = *(const f32x4_t*)(crp + d0a);
  const f32x4_t cr1 = *(const f32x4_t*)(crp + d0b);

  // ---- convert h to bf16 B-fragments (truncate) ----
  short8_t hf[8];
  #pragma unroll
  for (int k2 = 0; k2 < 4; ++k2) {
    const unsigned* a = (const unsigned*)&hL[2 * k2];
    const unsigned* b = (const unsigned*)&hL[2 * k2 + 1];
    union { unsigned u[4]; short8_t s; } pL;
    pL.u[0] = pk2(a[0], a[1]); pL.u[1] = pk2(a[2], a[3]);
    pL.u[2] = pk2(b[0], b[1]); pL.u[3] = pk2(b[2], b[3]);
    hf[k2] = pL.s;
    const unsigned* c_ = (const unsigned*)&hR[2 * k2];
    const unsigned* d_ = (const unsigned*)&hR[2 * k2 + 1];
    union { unsigned u[4]; short8_t s; } pR;
    pR.u[0] = pk2(c_[0], c_[1]); pR.u[1] = pk2(c_[2], c_[3]);
    pR.u[2] = pk2(d_[0], d_[1]); pR.u[3] = pk2(d_[2], d_[3]);
    hf[4 + k2] = pR.s;
  }

  // ---- GEMM: acc[dblk][gate], W streamed from L2 ----
  f32x4_t acc[2][5];
  #pragma unroll
  for (int db = 0; db < 2; ++db)
    #pragma unroll
    for (int g = 0; g < 5; ++g) {
      f32x4_t z = {0.0f, 0.0f, 0.0f, 0.0f};
      acc[db][g] = z;
    }

  const unsigned short* const wbase = Wt + (size_t)l16 * 256 + lq * 8;
  #pragma unroll
  for (int kk = 0; kk < 8; ++kk) {
    #pragma unroll
    for (int g = 0; g < 5; ++g) {
      const short8_t wf0 = *(const short8_t*)(
          wbase + (size_t)(g * 128 + w * 32) * 256 + kk * 32);
      const short8_t wf1 = *(const short8_t*)(
          wbase + (size_t)(g * 128 + w * 32 + 16) * 256 + kk * 32);
      acc[0][g] = __builtin_amdgcn_mfma_f32_16x16x32_bf16(wf0, hf[kk], acc[0][g], 0, 0, 0);
      acc[1][g] = __builtin_amdgcn_mfma_f32_16x16x32_bf16(wf1, hf[kk], acc[1][g], 0, 0, 0);
    }
  }

  // ---- epilogue: bias (L2-hot) + LSTM cell + stores ----
  if (valid) {
    float* const out_h = out;
    float* const out_c = out + (size_t)M * DDIM;
    #pragma unroll
    for (int db = 0; db < 2; ++db) {
      const int d0 = (db == 0) ? d0a : d0b;
      const f32x4_t clv = (db == 0) ? cl0 : cl1;
      const f32x4_t crv = (db == 0) ? cr0 : cr1;
      f32x4_t bs[5];
      #pragma unroll
      for (int g = 0; g < 5; ++g)
        bs[g] = *(const f32x4_t*)(bias + g * DDIM + d0);
      f32x4_t hv4, cv4;
      #pragma unroll
      for (int j = 0; j < 4; ++j) {
        const float gi = acc[db][0][j] + bs[0][j];
        const float go = acc[db][1][j] + bs[1][j];
        const float gu = acc[db][2][j] + bs[2][j];
        const float gl = acc[db][3][j] + bs[3][j];
        const float gr = acc[db][4][j] + bs[4][j];
        const float cn = sigf(gi) * tanh_fast(gu)
                       + sigf(gl) * clv[j] + sigf(gr) * crv[j];
        const float hn = sigf(go) * tanh_fast(cn);
        cv4[j] = cn; hv4[j] = hn;
      }
      const size_t off = (size_t)m * DDIM + d0;
      *(f32x4_t*)(out_h + off) = hv4;
      *(f32x4_t*)(out_c + off) = cv4;
    }
  }
}

extern "C" void kernel_launch(void* const* d_in, const int* in_sizes, int n_in,
                              void* d_out, int out_size, void* d_ws, size_t ws_size,
                              hipStream_t stream) {
  const float* h_bot  = (const float*)d_in[0];
  const float* c_bot  = (const float*)d_in[1];
  const float* h_buf  = (const float*)d_in[2];
  const float* c_buf  = (const float*)d_in[3];
  const int*   idx_bl = (const int*)d_in[4];
  const int*   idx_pl = (const int*)d_in[5];
  const int*   idx_br = (const int*)d_in[6];
  const int*   idx_pr = (const int*)d_in[7];
  const float* W      = (const float*)d_in[8];
  const float* bias   = (const float*)d_in[9];

  const int K = in_sizes[4];
  const int M = 2 * K;
  const int fiveD = in_sizes[9];               // 640
  const int twoD  = in_sizes[8] / fiveD;       // 256

  unsigned short* Wt = (unsigned short*)d_ws;  // [640][256] bf16 = 320 KB

  hipLaunchKernelGGL(convert_w_kernel, dim3(fiveD), dim3(twoD), 0, stream,
                     W, Wt, twoD, fiveD);

  const int grid = (M + 15) / 16;              // one 16-row tile per 256-thread block
  hipLaunchKernelGGL(treelstm_fused_kernel, dim3(grid), dim3(256), 0, stream,
                     h_bot, c_bot, h_buf, c_buf,
                     idx_bl, idx_pl, idx_br, idx_pr,
                     bias, Wt, (float*)d_out, K, M);
}

// Round 10
// 940.969 us; speedup vs baseline: 1.5687x; 1.2234x over previous
//
#include <hip/hip_runtime.h>

typedef __attribute__((ext_vector_type(8))) short short8_t;
typedef __attribute__((ext_vector_type(4))) float f32x4_t;

#define DDIM  128
#define BM    64          // K2 tile rows
#define NBLK2 512         // K2 persistent blocks (2/CU)

__device__ __forceinline__ unsigned short f2bf(float x) {
  union { float f; unsigned u; } v; v.f = x;
  unsigned r = v.u + 0x7FFFu + ((v.u >> 16) & 1u);   // RNE
  return (unsigned short)(r >> 16);
}

__device__ __forceinline__ float sigf(float x) {
  return __builtin_amdgcn_rcpf(1.0f + __expf(-x));
}
__device__ __forceinline__ float tanh_fast(float x) {
  return 2.0f * __builtin_amdgcn_rcpf(1.0f + __expf(-2.0f * x)) - 1.0f;
}

__device__ __forceinline__ void gload_lds16(const void* gp, void* lp) {
  __builtin_amdgcn_global_load_lds(
      (const __attribute__((address_space(1))) void*)gp,
      (__attribute__((address_space(3))) void*)lp, 16, 0, 0);
}

// Wt[c][k] = bf16(W[k][c]);  W:[256][640] f32, Wt:[640][256] bf16 (RNE)
__global__ void convert_w_kernel(const float* __restrict__ W,
                                 unsigned short* __restrict__ Wt,
                                 int twoD, int fiveD) {
  const int c = blockIdx.x;
  const int k = threadIdx.x;
  Wt[c * twoD + k] = f2bf(W[k * fiveD + c]);
}

// K1: gather h_l/h_r rows, pack to bf16, write swizzled 512B rows P[m].
// Row m chunk layout: logical 16B chunk c (elems c*8..c*8+8 of [h_l|h_r])
// stored at physical chunk c ^ ((m&7)<<2)  -> K2 ds_reads are 2-way (free).
__global__ __launch_bounds__(256)
void gather_pack_kernel(const float* __restrict__ h_bot,
                        const float* __restrict__ h_buf,
                        const int* __restrict__ idx_bl,
                        const int* __restrict__ idx_pl,
                        const int* __restrict__ idx_br,
                        const int* __restrict__ idx_pr,
                        unsigned short* __restrict__ P,
                        int K, int M) {
  const int m = blockIdx.x * 32 + (threadIdx.x >> 3);
  if (m >= M) return;
  const int seg  = threadIdx.x & 7;
  const int half = seg >> 2;          // 0: h_l, 1: h_r
  const int cs   = seg & 3;

  int idx;
  if (half == 0) idx = (m < K) ? idx_bl[m] : idx_pl[m - K];
  else           idx = (m < K) ? idx_br[m] : idx_pr[m - K];
  const float* const hb  = (m < K) ? h_bot : h_buf;
  const float* const src = hb + (size_t)idx * DDIM;

  unsigned short* const prow = P + (size_t)m * 256;
  const int key = (m & 7) << 2;

  #pragma unroll
  for (int q = 0; q < 4; ++q) {
    const int c = half * 16 + cs + 4 * q;       // logical chunk 0..31
    const float* sp = src + (cs + 4 * q) * 8;   // 8 f32 source elems
    const f32x4_t v0 = *(const f32x4_t*)(sp);
    const f32x4_t v1 = *(const f32x4_t*)(sp + 4);
    union { unsigned short us[8]; short8_t s; } pk;
    pk.us[0] = f2bf(v0[0]); pk.us[1] = f2bf(v0[1]);
    pk.us[2] = f2bf(v0[2]); pk.us[3] = f2bf(v0[3]);
    pk.us[4] = f2bf(v1[0]); pk.us[5] = f2bf(v1[1]);
    pk.us[6] = f2bf(v1[2]); pk.us[7] = f2bf(v1[3]);
    *(short8_t*)(prow + (size_t)(c ^ key) * 8) = pk.s;
  }
}

// K2: dense-staged GEMM + fused LSTM epilogue. Persistent, double-buffered.
__global__ __launch_bounds__(512, 4)
void gemm_kernel(const unsigned short* __restrict__ P,
                 const float* __restrict__ c_bot,
                 const float* __restrict__ c_buf,
                 const int* __restrict__ idx_bl,
                 const int* __restrict__ idx_pl,
                 const int* __restrict__ idx_br,
                 const int* __restrict__ idx_pr,
                 const float* __restrict__ bias,
                 const unsigned short* __restrict__ Wt,
                 float* __restrict__ out,
                 int K, int M, int ntiles) {
  __shared__ __align__(128) unsigned short A[2][BM * 256];   // 2 x 32 KB

  const int tid  = threadIdx.x;
  const int w    = tid >> 6;          // 0..7 -> d-block
  const int lane = tid & 63;
  const int l16  = lane & 15;
  const int lq   = lane >> 4;         // 0..3
  const int d0   = w * 16 + lq * 4;
  const int rkey = (l16 & 7) << 2;    // read-side chunk swizzle key

  // staging: thread copies 4 x 16B; dest is linear (wave-uniform + lane*16)
  const int srow0 = tid >> 5;         // 0..15
  const int schk  = tid & 31;

  float* const out_h = out;
  float* const out_c = out + (size_t)M * DDIM;

  const int step = gridDim.x;
  int t = blockIdx.x;
  if (t >= ntiles) return;

#define STAGE(tt, buf)                                                       \
  { _Pragma("unroll")                                                        \
    for (int j = 0; j < 4; ++j) {                                            \
      const int r = j * 16 + srow0;                                          \
      gload_lds16(P + ((size_t)(tt) * BM + r) * 256 + schk * 8,              \
                  &A[buf][r * 256 + schk * 8]);                              \
    } }

  STAGE(t, 0);
  __syncthreads();

  int cur = 0;
  for (;;) {
    const int tn = t + step;
    const bool more = (tn < ntiles);

    // (1) issue next tile's dense stage (in flight across GEMM + barrier)
    if (more) STAGE(tn, cur ^ 1);

    // (2) c-gathers for this tile (consumed in epilogue; GEMM hides latency)
    const int tb = t * BM;
    f32x4_t cl[4], cr[4];
    #pragma unroll
    for (int mt = 0; mt < 4; ++mt) {
      int m = tb + mt * 16 + l16; if (m >= M) m = M - 1;
      const int il = (m < K) ? idx_bl[m] : idx_pl[m - K];
      const int ir = (m < K) ? idx_br[m] : idx_pr[m - K];
      const float* cb = (m < K) ? c_bot : c_buf;
      cl[mt] = *(const f32x4_t*)(cb + (size_t)il * DDIM + d0);
      cr[mt] = *(const f32x4_t*)(cb + (size_t)ir * DDIM + d0);
    }

    // (3) GEMM: 4 m-tiles x 5 gates, K=256
    f32x4_t acc[4][5];
    #pragma unroll
    for (int mt = 0; mt < 4; ++mt)
      #pragma unroll
      for (int g = 0; g < 5; ++g) {
        f32x4_t z = {0.0f, 0.0f, 0.0f, 0.0f};
        acc[mt][g] = z;
      }

    const unsigned short* const wb = Wt + (size_t)(w * 16 + l16) * 256 + lq * 8;
    const unsigned short* const ab = &A[cur][l16 * 256];

    #pragma unroll
    for (int kk = 0; kk < 8; ++kk) {
      short8_t hf[4];
      #pragma unroll
      for (int mt = 0; mt < 4; ++mt)
        hf[mt] = *(const short8_t*)(ab + mt * (16 * 256) +
                                    (size_t)(((kk * 4 + lq) ^ rkey)) * 8);
      #pragma unroll
      for (int g = 0; g < 5; ++g) {
        const short8_t wf =
            *(const short8_t*)(wb + (size_t)g * (128 * 256) + kk * 32);
        #pragma unroll
        for (int mt = 0; mt < 4; ++mt)
          acc[mt][g] = __builtin_amdgcn_mfma_f32_16x16x32_bf16(
              wf, hf[mt], acc[mt][g], 0, 0, 0);
      }
    }

    // (4) epilogue: bias + LSTM cell + stores
    f32x4_t bs[5];
    #pragma unroll
    for (int g = 0; g < 5; ++g)
      bs[g] = *(const f32x4_t*)(bias + g * DDIM + d0);

    #pragma unroll
    for (int mt = 0; mt < 4; ++mt) {
      const int m = tb + mt * 16 + l16;
      if (m < M) {
        f32x4_t hv4, cv4;
        #pragma unroll
        for (int j = 0; j < 4; ++j) {
          const float gi = acc[mt][0][j] + bs[0][j];
          const float go = acc[mt][1][j] + bs[1][j];
          const float gu = acc[mt][2][j] + bs[2][j];
          const float gl = acc[mt][3][j] + bs[3][j];
          const float gr = acc[mt][4][j] + bs[4][j];
          const float cn = sigf(gi) * tanh_fast(gu)
                         + sigf(gl) * cl[mt][j] + sigf(gr) * cr[mt][j];
          const float hn = sigf(go) * tanh_fast(cn);
          cv4[j] = cn; hv4[j] = hn;
        }
        const size_t off = (size_t)m * DDIM + d0;
        *(f32x4_t*)(out_h + off) = hv4;
        *(f32x4_t*)(out_c + off) = cv4;
      }
    }

    if (!more) break;
    __syncthreads();   // drains stage -> buf[cur^1] ready; bufc reads done
    cur ^= 1;
    t = tn;
  }
#undef STAGE
}

extern "C" void kernel_launch(void* const* d_in, const int* in_sizes, int n_in,
                              void* d_out, int out_size, void* d_ws, size_t ws_size,
                              hipStream_t stream) {
  const float* h_bot  = (const float*)d_in[0];
  const float* c_bot  = (const float*)d_in[1];
  const float* h_buf  = (const float*)d_in[2];
  const float* c_buf  = (const float*)d_in[3];
  const int*   idx_bl = (const int*)d_in[4];
  const int*   idx_pl = (const int*)d_in[5];
  const int*   idx_br = (const int*)d_in[6];
  const int*   idx_pr = (const int*)d_in[7];
  const float* W      = (const float*)d_in[8];
  const float* bias   = (const float*)d_in[9];

  const int K = in_sizes[4];
  const int M = 2 * K;
  const int fiveD = in_sizes[9];               // 640
  const int twoD  = in_sizes[8] / fiveD;       // 256

  unsigned short* Wt = (unsigned short*)d_ws;  // [640][256] bf16 = 320 KB

  // Packed bf16 A lives in the out_h region: K1 writes P[m] (512B/row),
  // K2 stages P[t] then overwrites out_h[t] strictly afterwards (same block).
  unsigned short* P = (unsigned short*)d_out;

  hipLaunchKernelGGL(convert_w_kernel, dim3(fiveD), dim3(twoD), 0, stream,
                     W, Wt, twoD, fiveD);

  hipLaunchKernelGGL(gather_pack_kernel, dim3((M + 31) / 32), dim3(256), 0, stream,
                     h_bot, h_buf, idx_bl, idx_pl, idx_br, idx_pr,
                     P, K, M);

  const int ntiles = (M + BM - 1) / BM;
  const int grid = (ntiles < NBLK2) ? ntiles : NBLK2;
  hipLaunchKernelGGL(gemm_kernel, dim3(grid), dim3(512), 0, stream,
                     P, c_bot, c_buf,
                     idx_bl, idx_pl, idx_br, idx_pr,
                     bias, Wt, (float*)d_out, K, M, ntiles);
}